// Round 2
// baseline (672.639 us; speedup 1.0000x reference)
//
#include <hip/hip_runtime.h>
#include <hip/hip_bf16.h>
#include <math.h>

#define IN_F    4096
#define OUT_F   4096
#define N_TOK   8192
#define GROUP   128
#define NSTAGE  4
#define NPAIRS  2048   // IN_F/2 pairs per stage
#define QMAXF   15.0

typedef unsigned short u16;
typedef __bf16 bf16x8 __attribute__((ext_vector_type(8)));
typedef float  f32x4  __attribute__((ext_vector_type(4)));

struct alignas(8) U16x4 { u16 x, y, z, w; };

__device__ __forceinline__ u16 f2bf(float f) {
    unsigned u = __float_as_uint(f);
    unsigned r = (u + 0x7fffu + ((u >> 16) & 1u)) >> 16;   // RNE
    return (u16)r;
}

__device__ __forceinline__ void gl_lds16(const void* g, void* l) {
    __builtin_amdgcn_global_load_lds(
        (const __attribute__((address_space(1))) void*)g,
        (__attribute__((address_space(3))) void*)l,
        16, 0, 0);
}

__device__ __forceinline__ void bar() {
    asm volatile("" ::: "memory");
    __builtin_amdgcn_s_barrier();
    asm volatile("" ::: "memory");
}

// ---------------------------------------------------------------- tables ----
__global__ void make_tabs(const float* __restrict__ theta,
                          double* __restrict__ ctab, double* __restrict__ stab) {
    int i = blockIdx.x * 256 + threadIdx.x;
    if (i < NSTAGE * NPAIRS) {
        double t = (double)theta[i];
        ctab[i] = cos(t);
        stab[i] = sin(t);
    }
}

// ------------------------------------------------------------- transform ----
// One WAVE per (row, group): block-diagonal chain in LDS doubles, wave-sync.
__global__ __launch_bounds__(256) void build_w(
    const float* __restrict__ weight, const float* __restrict__ cs,
    const float* __restrict__ qs, const float* __restrict__ qzp,
    const int* __restrict__ pairs,
    const double* __restrict__ ctab, const double* __restrict__ stab,
    u16* __restrict__ wb) {
    __shared__ double gbuf[4][GROUP];
    const int wave = threadIdx.x >> 6, l = threadIdx.x & 63;
    const int task = blockIdx.x * 4 + wave;        // 4096*32 tasks
    const int o = task >> 5, g = task & 31;
    double* gb = gbuf[wave];
    const int e0 = g * GROUP;

    float2 wv = *(const float2*)(weight + (size_t)o * IN_F + e0 + 2 * l);
    float2 cv = *(const float2*)(cs + e0 + 2 * l);
    gb[2 * l]     = (double)wv.x * (double)cv.x;
    gb[2 * l + 1] = (double)wv.y * (double)cv.y;
    __builtin_amdgcn_wave_barrier();

    const int2* prs = (const int2*)pairs;          // (i,j) pairs, 8B aligned

    for (int r = 0; r < NSTAGE; ++r) {
        int2 p = prs[r * (IN_F / 2) + g * 64 + l];
        double c = ctab[r * NPAIRS + g * 64 + l];
        double s = stab[r * NPAIRS + g * 64 + l];
        double xi = gb[p.x], xj = gb[p.y];
        __builtin_amdgcn_wave_barrier();
        gb[p.x] =  xi * c + xj * s;
        gb[p.y] = -xi * s + xj * c;
        __builtin_amdgcn_wave_barrier();
    }

    {
        double s   = fmin(fmax((double)qs[o * 32 + g], 1e-5), 1e5);
        double rzp = fmin(fmax(-rint((double)qzp[o * 32 + g]), 0.0), QMAXF);
#pragma unroll
        for (int e = 2 * l; e <= 2 * l + 1; ++e) {
            double q = rint(gb[e] / s) + rzp;
            q = fmin(fmax(q, 0.0), QMAXF);
            gb[e] = (q - rzp) * s;
        }
        __builtin_amdgcn_wave_barrier();
    }

    for (int r = NSTAGE - 1; r >= 0; --r) {
        int2 p = prs[r * (IN_F / 2) + g * 64 + l];
        double c = ctab[r * NPAIRS + g * 64 + l];
        double s = stab[r * NPAIRS + g * 64 + l];
        double xi = gb[p.x], xj = gb[p.y];
        __builtin_amdgcn_wave_barrier();
        gb[p.x] = xi * c - xj * s;
        gb[p.y] = xi * s + xj * c;
        __builtin_amdgcn_wave_barrier();
    }

    unsigned lo = f2bf((float)(gb[2 * l]     / (double)cv.x));
    unsigned hi = f2bf((float)(gb[2 * l + 1] / (double)cv.y));
    *(unsigned*)(wb + (size_t)o * IN_F + e0 + 2 * l) = lo | (hi << 16);
}

// ----------------------------------------------------------------- cast x ---
__global__ void cast_x(const float* __restrict__ x, u16* __restrict__ xb) {
    size_t i = ((size_t)blockIdx.x * 256 + threadIdx.x) * 4;
    float4 v = *(const float4*)(x + i);
    U16x4 o;
    o.x = f2bf(v.x); o.y = f2bf(v.y); o.z = f2bf(v.z); o.w = f2bf(v.w);
    *(U16x4*)(xb + i) = o;
}

// ------------------------------------------------------------------ GEMM ----
// C[m,n] = sum_k A[m,k] * B[n,k] + bias[n]   (A: M x K, B: N x K, both bf16)
//
// m201-style 8-phase schedule: 256x256 tile, 512 thr / 8 waves (2M x 4N,
// wave tile 128x64), BK=64, 2-slot LDS dbuf (128 KiB). 4 phases per K-tile
// (quadrant = k-step x n-half), each phase:
//   { issue ds_reads (10/2/10/2) ; issue half-tile stages ; [vmcnt]
//     ; s_barrier ; setprio(1) ; 16 MFMA ; setprio(0) ; s_barrier }
// Staging by free-window: P1 stages B(g+1) (B halves freed by previous
// group's final barrier); P4 stages A(g+2) into the CURRENT slot (A halves
// freed after P3's trailing barrier). Counted waits (issue-order exact):
// vmcnt(8) after prologue; vmcnt(4) at P4 (only A(g+2) in flight);
// vmcnt(0) only at the last tile. Never drains mid-loop -- the m97 stall.
// LDS chunk-XOR swizzle (chunk ^= row&7) on pre-swizzled global source:
// ds_read_b128 is 2-way per bank = free (m136); gl_lds dest stays linear.
__global__ __launch_bounds__(512, 2) void gemm_bt(
    const u16* __restrict__ A, const u16* __restrict__ B,
    const float* __restrict__ bias, float* __restrict__ C) {
    constexpr int K = IN_F;
    constexpr int N = OUT_F;
    constexpr int NGRP = K / 64;                     // 64 K-tiles
    constexpr int TIL = 256 * 64;                    // u16 per slot (32 KB)
    __shared__ __align__(16) u16 As[2][TIL];         // 64 KB
    __shared__ __align__(16) u16 Bs[2][TIL];         // 64 KB

    const int tid  = threadIdx.x;
    const int wave = tid >> 6, lane = tid & 63;
    const int lrow = lane & 15, lq = lane >> 4;
    const int wm = wave >> 2, wn = wave & 3;         // 2x4 wave grid

    // XCD-bijective swizzle (512 wgs % 8 == 0)
    const int wg = (blockIdx.x & 7) * 64 + (blockIdx.x >> 3);
    const int mt = wg & 31, nt = wg >> 5;
    const int m0 = mt * 256, n0 = nt * 256;

    // staging: half-tile = 128 rows x 64 cols x 2B = 16 KB = 2 rounds of
    // 512 thr x 16B. Linear LDS dest; swizzled global source chunk.
    const int prow = tid >> 3;                       // 0..63 within round
    const int pch  = (tid & 7) ^ ((tid >> 3) & 7);   // pre-swizzled src chunk
    const u16* pA = A + (size_t)(m0 + prow) * K + pch * 8;
    const u16* pB = B + (size_t)(n0 + prow) * K + pch * 8;

#define STAGE_A(slot, t) do {                                                  \
        _Pragma("unroll")                                                      \
        for (int hr_ = 0; hr_ < 4; ++hr_) {                                    \
            const int h_ = hr_ >> 1, r_ = hr_ & 1;                             \
            gl_lds16(pA + (size_t)(h_ * 128 + r_ * 64) * K + (t) * 64,         \
                     &As[slot][h_ * 8192 + r_ * 4096 + (wave << 9)]);          \
        }                                                                      \
    } while (0)
#define STAGE_B(slot, t) do {                                                  \
        _Pragma("unroll")                                                      \
        for (int hr_ = 0; hr_ < 4; ++hr_) {                                    \
            const int h_ = hr_ >> 1, r_ = hr_ & 1;                             \
            gl_lds16(pB + (size_t)(h_ * 128 + r_ * 64) * K + (t) * 64,         \
                     &Bs[slot][h_ * 8192 + r_ * 4096 + (wave << 9)]);          \
        }                                                                      \
    } while (0)

    // fragment reads: row stride 64 u16 (128 B); global chunk (ks*4+lq)
    // lives at LDS chunk (ks*4+lq)^(row&7)
#define RD_A(ks) do {                                                          \
        _Pragma("unroll")                                                      \
        for (int mi_ = 0; mi_ < 8; ++mi_) {                                    \
            const int ar_ = (wm << 7) + (mi_ << 4) + lrow;                     \
            af[mi_] = *(const bf16x8*)&as_[(ar_ << 6) +                        \
                (((((ks) << 2) | lq) ^ (ar_ & 7)) << 3)];                      \
        }                                                                      \
    } while (0)
#define RD_B(ks, nj0) do {                                                     \
        const int br0_ = (wn << 6) + ((nj0) << 4) + lrow;                      \
        b0 = *(const bf16x8*)&bs_[(br0_ << 6) +                                \
                (((((ks) << 2) | lq) ^ (br0_ & 7)) << 3)];                     \
        b1 = *(const bf16x8*)&bs_[((br0_ + 16) << 6) +                         \
                (((((ks) << 2) | lq) ^ (br0_ & 7)) << 3)];                     \
    } while (0)

#define MF2(nj0) do {                                                          \
        __builtin_amdgcn_s_setprio(1);                                         \
        _Pragma("unroll")                                                      \
        for (int mi_ = 0; mi_ < 8; ++mi_) {                                    \
            acc[mi_][nj0] = __builtin_amdgcn_mfma_f32_16x16x32_bf16(           \
                af[mi_], b0, acc[mi_][nj0], 0, 0, 0);                          \
            acc[mi_][(nj0) + 1] = __builtin_amdgcn_mfma_f32_16x16x32_bf16(     \
                af[mi_], b1, acc[mi_][(nj0) + 1], 0, 0, 0);                    \
        }                                                                      \
        __builtin_amdgcn_s_setprio(0);                                         \
    } while (0)

    f32x4 acc[8][4];
#pragma unroll
    for (int i = 0; i < 8; ++i)
#pragma unroll
        for (int j = 0; j < 4; ++j) acc[i][j] = (f32x4){0.f, 0.f, 0.f, 0.f};

    // prologue: tiles 0,1 fully staged (16 loads); retire tile 0, keep tile 1
    STAGE_A(0, 0); STAGE_B(0, 0); STAGE_A(1, 1); STAGE_B(1, 1);
    asm volatile("s_waitcnt vmcnt(8)" ::: "memory");
    __builtin_amdgcn_s_barrier();
    asm volatile("" ::: "memory");

#pragma unroll 2
    for (int g = 0; g < NGRP; ++g) {
        u16* as_ = As[g & 1];
        u16* bs_ = Bs[g & 1];
        bf16x8 af[8], b0, b1;

        // ---- P1: ks=0, nj={0,1}  (10 ds_read; stage B(g+1))
        RD_A(0);
        RD_B(0, 0);
        if (g >= 1 && g + 1 < NGRP) STAGE_B((g + 1) & 1, g + 1);
        bar();
        MF2(0);
        bar();

        // ---- P2: ks=0, nj={2,3}  (2 ds_read)
        RD_B(0, 2);
        bar();
        MF2(2);
        bar();

        // ---- P3: ks=1, nj={0,1}  (10 ds_read; A halves of tile g now free)
        RD_A(1);
        RD_B(1, 0);
        bar();
        MF2(0);
        bar();

        // ---- P4: ks=1, nj={2,3}  (2 ds_read; stage A(g+2) into this slot;
        //      counted wait gates tile g+1: only A(g+2) may stay in flight)
        RD_B(1, 2);
        if (g + 2 < NGRP) {
            STAGE_A(g & 1, g + 2);
            asm volatile("s_waitcnt vmcnt(4)" ::: "memory");
        } else if (g + 1 < NGRP) {
            asm volatile("s_waitcnt vmcnt(0)" ::: "memory");
        }
        bar();
        MF2(2);
        bar();
    }

#undef STAGE_A
#undef STAGE_B
#undef RD_A
#undef RD_B
#undef MF2

    // epilogue: C/D layout col = lane&15, row = (lane>>4)*4 + reg
#pragma unroll
    for (int mi = 0; mi < 8; ++mi) {
        int rb = m0 + wm * 128 + mi * 16 + lq * 4;
#pragma unroll
        for (int nj = 0; nj < 4; ++nj) {
            int col = n0 + wn * 64 + nj * 16 + lrow;
            float bv = bias[col];
#pragma unroll
            for (int r = 0; r < 4; ++r)
                C[(size_t)(rb + r) * N + col] = acc[mi][nj][r] + bv;
        }
    }
}

// ---------------------------------------------------------------- launch ----
extern "C" void kernel_launch(void* const* d_in, const int* in_sizes, int n_in,
                              void* d_out, int out_size, void* d_ws, size_t ws_size,
                              hipStream_t stream) {
    const float* x    = (const float*)d_in[0];
    const float* w    = (const float*)d_in[1];
    const float* bias = (const float*)d_in[2];
    const float* cs   = (const float*)d_in[3];
    const float* th   = (const float*)d_in[4];
    const float* qs   = (const float*)d_in[5];
    const float* qzp  = (const float*)d_in[6];
    const int*   pr   = (const int*)d_in[7];
    float* out = (float*)d_out;

    char* ws = (char*)d_ws;
    double* ctab = (double*)ws;                                  // 64 KB
    double* stab = (double*)(ws + 65536);                        // 64 KB
    u16*    xb   = (u16*)(ws + 131072);                          // 64 MB
    u16*    wb   = (u16*)(ws + 131072 + (size_t)N_TOK * IN_F * 2);  // 32 MB

    hipLaunchKernelGGL(make_tabs, dim3((NSTAGE * NPAIRS + 255) / 256), dim3(256),
                       0, stream, th, ctab, stab);
    hipLaunchKernelGGL(build_w, dim3(OUT_F * 32 / 4), dim3(256), 0, stream,
                       w, cs, qs, qzp, pr, ctab, stab, wb);
    hipLaunchKernelGGL(cast_x, dim3(N_TOK * IN_F / 4 / 256), dim3(256), 0, stream,
                       x, xb);
    hipLaunchKernelGGL(gemm_bt, dim3((N_TOK / 256) * (OUT_F / 256)), dim3(512),
                       0, stream, xb, wb, bias, out);
}